// Round 9
// baseline (339.367 us; speedup 1.0000x reference)
//
#include <hip/hip_runtime.h>

#define B_ 64
#define D_ 256
#define T_ 1024
#define NC_ 1024
#define DT_ (D_ * T_)              // 262144
#define NPTS_ (B_ * T_)            // 65536

#define QSZ_   16777216            // B*D*T
#define LOSS_OFF 16777216
#define CMT_OFF  16777217
#define IDX_OFF  16777218
#define PERP_OFF 16842754

typedef _Float16 half8 __attribute__((ext_vector_type(8)));
typedef float f32x4 __attribute__((ext_vector_type(4)));

// LDS row stride for x tiles: 256 k + 8 pad halves = 264 (528B, 16B-aligned)
#define XROW_ 264
#define XLO_OFF_ (64 * XROW_)      // xs_lo starts here (halfs)

// ---------------- Kernel P: split embed into frag-order hi/lo + f32 norms ---
// ehi/elo layout: frag-major. For code-group g (16 codes), k-chunk kc (32 k),
// lane l: element j holds e[g*16 + (l&15)][kc*32 + (l>>4)*8 + j].
// Stored at half-offset ((g*8 + kc)*64 + l)*8 + j -> wave loads 1KB contiguous.
__global__ void prep_embed(const float* __restrict__ embed,
                           _Float16* __restrict__ ehi,
                           _Float16* __restrict__ elo,
                           float* __restrict__ normf) {
  int g = blockIdx.x;              // 64 blocks
  int tid = threadIdx.x;           // 256
  int w = tid >> 6, l = tid & 63;

#pragma unroll
  for (int ii = 0; ii < 2; ++ii) {
    int kc = w * 2 + ii;
    int code = g * 16 + (l & 15);
    int k0 = kc * 32 + (l >> 4) * 8;
    const float* src = embed + (size_t)code * D_ + k0;
    half8 hh, ll;
#pragma unroll
    for (int j = 0; j < 8; ++j) {
      float v = src[j];
      _Float16 h = (_Float16)v;
      _Float16 lo = (_Float16)(v - (float)h);
      hh[j] = h;
      ll[j] = lo;
    }
    size_t off = ((size_t)(g * 8 + kc) * 64 + l) * 8;
    *(half8*)(ehi + off) = hh;
    *(half8*)(elo + off) = ll;
  }

  // f64-accumulated norms (stored f32): code = g*16 + tid>>4, seg (tid&15)*16
  int code = g * 16 + (tid >> 4);
  int ks = (tid & 15) * 16;
  const float* src = embed + (size_t)code * D_ + ks;
  double s = 0.0;
#pragma unroll
  for (int j = 0; j < 16; ++j) {
    double v = src[j];
    s += v * v;
  }
#pragma unroll
  for (int m = 1; m < 16; m <<= 1) s += __shfl_xor(s, m, 64);
  if ((tid & 15) == 0) normf[code] = (float)s;
}

// ---------------- argmin kernel helpers -------------------------------------
__device__ __forceinline__ void loadB2(half8 (&BH)[2], half8 (&BL)[2],
                                       const _Float16* __restrict__ ehi,
                                       const _Float16* __restrict__ elo,
                                       int w, int l, int ng, int kc) {
#pragma unroll
  for (int n = 0; n < 2; ++n) {
    int g = ng * 8 + w * 2 + n;
    size_t off = ((size_t)(g * 8 + kc) * 64 + l) * 8;
    BH[n] = *(const half8*)(ehi + off);
    BL[n] = *(const half8*)(elo + off);
  }
}

__device__ __forceinline__ void loadA(half8 (&AH)[4], half8 (&AL)[4],
                                      const _Float16* xs, int lrow, int lk,
                                      int kc) {
#pragma unroll
  for (int m = 0; m < 4; ++m) {
    const _Float16* p = &xs[(m * 16 + lrow) * XROW_ + kc * 32 + lk];
    AH[m] = *(const half8*)p;
    AL[m] = *(const half8*)(p + XLO_OFF_);
  }
}

__device__ __forceinline__ void mfma24(f32x4 (&acc)[4][2], half8 (&AH)[4],
                                       half8 (&AL)[4], half8 (&BH)[2],
                                       half8 (&BL)[2]) {
#pragma unroll
  for (int m = 0; m < 4; ++m)
#pragma unroll
    for (int n = 0; n < 2; ++n) {
      acc[m][n] =
          __builtin_amdgcn_mfma_f32_16x16x32_f16(AH[m], BH[n], acc[m][n], 0, 0, 0);
      acc[m][n] =
          __builtin_amdgcn_mfma_f32_16x16x32_f16(AL[m], BH[n], acc[m][n], 0, 0, 0);
      acc[m][n] =
          __builtin_amdgcn_mfma_f32_16x16x32_f16(AH[m], BL[n], acc[m][n], 0, 0, 0);
    }
}

// ---------------- Kernel B: MFMA distance GEMM + argmin ---------------------
// 1024 blocks x 256 threads (4 waves). Block owns 64 points (one b, 64 t).
// x tile staged once in LDS as f16 hi/lo (74240 B total -> 2 blocks/CU).
// Wave covers 32 codes per ng (2 N-frags), 8 ngs -> 256 codes/wave.
// SOFTWARE PIPELINE: both A (LDS) and B (L2) operand sets are prefetched
// exactly one kc-step ahead into the alternate register set, so every
// load flies under the previous step's 24-MFMA chain. Live state:
// A 2x32 + B 2x16 + acc 32 + fold 32 ~ 175 regs (fits (256,2) cap 256).
__global__ __launch_bounds__(256, 2) void argmin_kernel(
    const float* __restrict__ inputs, const _Float16* __restrict__ ehi,
    const _Float16* __restrict__ elo, const float* __restrict__ normf,
    float* __restrict__ idx_out, int* __restrict__ counts,
    double* __restrict__ mse_acc) {
  __shared__ _Float16 xs[2 * 64 * XROW_];  // hi then lo, 67584 B
  __shared__ float normf_lds[1024];        // 4096 B
  __shared__ double part[256];             // 2048 B (aliased by cand at tail)
  __shared__ double xn2s[64];              // 512 B

  float* candv = (float*)part;             // [4][64] floats, tail only
  int* candi = (int*)(part + 128);         // [4][64] ints, tail only

  int tid = threadIdx.x;
  int blk = blockIdx.x;            // point block: 64 points
  int b = blk >> 4, t0 = (blk & 15) * 64;
  size_t base = (size_t)b * DT_ + t0;

  // ---- stage x tile: f32 -> (hi,lo) f16, transpose [d][t] -> [t][k=d] ----
  {
    int t = tid & 63, dgrp = tid >> 6;
    const float* src = inputs + base + t;
    double s = 0.0;
#pragma unroll 4
    for (int i = 0; i < 32; ++i) {
      int d = dgrp * 64 + i * 2;
      float v0 = src[(size_t)d * T_];
      float v1 = src[(size_t)(d + 1) * T_];
      s += (double)v0 * v0 + (double)v1 * v1;
      _Float16 h0 = (_Float16)v0, h1 = (_Float16)v1;
      _Float16 e0 = (_Float16)(v0 - (float)h0);
      _Float16 e1 = (_Float16)(v1 - (float)h1);
      union {
        _Float16 h[2];
        unsigned u;
      } ph, pl;
      ph.h[0] = h0; ph.h[1] = h1;
      pl.h[0] = e0; pl.h[1] = e1;
      *(unsigned*)&xs[t * XROW_ + d] = ph.u;
      *(unsigned*)&xs[XLO_OFF_ + t * XROW_ + d] = pl.u;
    }
    part[tid] = s;
    // stage f32 norms table (4 KB)
    ((float4*)normf_lds)[tid] = ((const float4*)normf)[tid];
  }
  __syncthreads();
  if (tid < 64)
    xn2s[tid] = part[tid] + part[64 + tid] + part[128 + tid] + part[192 + tid];
  __syncthreads();

  int w = tid >> 6, l = tid & 63;
  int lrow = l & 15;
  int lk = (l >> 4) * 8;

  // per-lane point slots: p_local = m*16 + (l>>4)*4 + r
  float bestv[4][4];
  int besti[4][4];
#pragma unroll
  for (int m = 0; m < 4; ++m)
#pragma unroll
    for (int r = 0; r < 4; ++r) {
      bestv[m][r] = 1e30f;
      besti[m][r] = 0;
    }

  // pipeline prologue: prime set A with (ng=0, kc=0)
  half8 ahA[4], alA[4], ahB[4], alB[4];
  half8 bhA[2], blA[2], bhB[2], blB[2];
  loadB2(bhA, blA, ehi, elo, w, l, 0, 0);
  loadA(ahA, alA, xs, lrow, lk, 0);

#define STEP_TO_B(NGB, KCB, KCA)                       \
  loadB2(bhB, blB, ehi, elo, w, l, NGB, KCB);          \
  loadA(ahB, alB, xs, lrow, lk, KCA);                  \
  mfma24(acc, ahA, alA, bhA, blA);

#define STEP_TO_A(NGB, KCB, KCA)                       \
  loadB2(bhA, blA, ehi, elo, w, l, NGB, KCB);          \
  loadA(ahA, alA, xs, lrow, lk, KCA);                  \
  mfma24(acc, ahB, alB, bhB, blB);

#pragma unroll 1
  for (int ng = 0; ng < 8; ++ng) {
    f32x4 acc[4][2];
#pragma unroll
    for (int m = 0; m < 4; ++m)
#pragma unroll
      for (int n = 0; n < 2; ++n) acc[m][n] = (f32x4){0.f, 0.f, 0.f, 0.f};

    int ngn = (ng + 1) & 7;
    STEP_TO_B(ng, 1, 1)
    STEP_TO_A(ng, 2, 2)
    STEP_TO_B(ng, 3, 3)
    STEP_TO_A(ng, 4, 4)
    STEP_TO_B(ng, 5, 5)
    STEP_TO_A(ng, 6, 6)
    STEP_TO_B(ng, 7, 7)
    STEP_TO_A(ngn, 0, 0)   // prefetch next ng's first step; compute set B

    // ---- f32 fold: key = nrm - 2*dot (xn2-free; strict < keeps low-index
    // ties because c is strictly increasing per thread) ----
#pragma unroll
    for (int n = 0; n < 2; ++n) {
      int c = (ng * 8 + w * 2 + n) * 16 + lrow;
      float nf = normf_lds[c];
#pragma unroll
      for (int m = 0; m < 4; ++m)
#pragma unroll
        for (int r = 0; r < 4; ++r) {
          float df = fmaf(-2.0f, acc[m][n][r], nf);
          if (df < bestv[m][r]) {
            bestv[m][r] = df;
            besti[m][r] = c;
          }
        }
    }
  }
#undef STEP_TO_B
#undef STEP_TO_A

  // reduce across the 16 code-lanes of each quarter
#pragma unroll
  for (int msk = 1; msk < 16; msk <<= 1) {
#pragma unroll
    for (int m = 0; m < 4; ++m)
#pragma unroll
      for (int r = 0; r < 4; ++r) {
        float ov = __shfl_xor(bestv[m][r], msk, 64);
        int oi = __shfl_xor(besti[m][r], msk, 64);
        if (ov < bestv[m][r] || (ov == bestv[m][r] && oi < besti[m][r])) {
          bestv[m][r] = ov;
          besti[m][r] = oi;
        }
      }
  }
  if (lrow == 0) {
    int q = l >> 4;
#pragma unroll
    for (int m = 0; m < 4; ++m)
#pragma unroll
      for (int r = 0; r < 4; ++r) {
        candv[w * 64 + m * 16 + q * 4 + r] = bestv[m][r];
        candi[w * 64 + m * 16 + q * 4 + r] = besti[m][r];
      }
  }
  __syncthreads();

  if (tid < 64) {
    float bv = candv[tid];
    int bi = candi[tid];
#pragma unroll
    for (int w2 = 1; w2 < 4; ++w2) {
      float ov = candv[w2 * 64 + tid];
      int oi = candi[w2 * 64 + tid];
      if (ov < bv || (ov == bv && oi < bi)) {
        bv = ov;
        bi = oi;
      }
    }
    int p = blk * 64 + tid;
    idx_out[p] = (float)bi;
    atomicAdd(&counts[bi], 1);
    // MSE: dist = ||x||^2 + (nrm - 2*dot) = xn2 + key
    double s = xn2s[tid] + (double)bv;
    for (int msk = 32; msk; msk >>= 1) s += __shfl_down(s, msk, 64);
    if (tid == 0) atomicAdd(mse_acc, s);
  }
}

// ---------------- Kernel C: gather quantized rows, coalesced write ----------
__global__ __launch_bounds__(256) void quantize_kernel(
    const float* __restrict__ embed, const float* __restrict__ idx_f,
    float* __restrict__ qout) {
  __shared__ float qs[64 * 257];
  __shared__ int lidx[64];

  int tid = threadIdx.x;
  int bx = blockIdx.x;
  int b = bx >> 4;
  int t0 = (bx & 15) * 64;

  if (tid < 64) lidx[tid] = (int)idx_f[b * T_ + t0 + tid];
  __syncthreads();

#pragma unroll 4
  for (int p = 0; p < 64; ++p) {
    qs[p * 257 + tid] = embed[(size_t)lidx[p] * D_ + tid];
  }
  __syncthreads();

  size_t base = (size_t)b * DT_ + t0;
#pragma unroll 4
  for (int i = 0; i < 64; ++i) {
    int d = i * 4 + (tid >> 6);
    int p = tid & 63;
    qout[base + (size_t)d * T_ + p] = qs[p * 257 + d];
  }
}

// ---------------- Kernel D: finalize scalars --------------------------------
__global__ void finalize_kernel(const int* __restrict__ counts,
                                const double* __restrict__ mse_acc,
                                float* __restrict__ out) {
  int tid = threadIdx.x;  // 1024
  double p = (double)counts[tid] / (double)NPTS_;
  double s = p * log(p + 1e-10);
  for (int m = 32; m; m >>= 1) s += __shfl_down(s, m, 64);
  __shared__ double red[16];
  if ((tid & 63) == 0) red[tid >> 6] = s;
  __syncthreads();
  if (tid == 0) {
    double tot = 0.0;
    for (int i = 0; i < 16; ++i) tot += red[i];
    double mse = *mse_acc / (double)QSZ_;
    out[LOSS_OFF] = (float)(mse * 1.2);
    out[CMT_OFF] = (float)mse;
    out[PERP_OFF] = (float)exp(-tot);
  }
}

// ---------------- launch ----------------------------------------------------
extern "C" void kernel_launch(void* const* d_in, const int* in_sizes, int n_in,
                              void* d_out, int out_size, void* d_ws,
                              size_t ws_size, hipStream_t stream) {
  const float* inputs = (const float*)d_in[0];
  const float* embed = (const float*)d_in[1];
  float* out = (float*)d_out;

  char* ws = (char*)d_ws;
  _Float16* ehi = (_Float16*)ws;                         // 512 KB
  _Float16* elo = (_Float16*)(ws + 524288);              // 512 KB
  float* normf = (float*)(ws + 1048576);                 // 4 KB
  int* counts = (int*)(ws + 1048576 + 4096);             // 4 KB
  double* mse = (double*)(ws + 1048576 + 8192);          // 8 B

  hipMemsetAsync(ws + 1048576 + 4096, 0, 4096 + 8, stream);

  prep_embed<<<64, 256, 0, stream>>>(embed, ehi, elo, normf);
  argmin_kernel<<<1024, 256, 0, stream>>>(inputs, ehi, elo, normf,
                                          out + IDX_OFF, counts, mse);
  quantize_kernel<<<1024, 256, 0, stream>>>(embed, out + IDX_OFF, out);
  finalize_kernel<<<1, 1024, 0, stream>>>(counts, mse, out);
}

// Round 10
// 197.806 us; speedup vs baseline: 1.7157x; 1.7157x over previous
//
#include <hip/hip_runtime.h>

#define B_ 64
#define D_ 256
#define T_ 1024
#define NC_ 1024
#define DT_ (D_ * T_)              // 262144
#define NPTS_ (B_ * T_)            // 65536

#define QSZ_   16777216            // B*D*T
#define LOSS_OFF 16777216
#define CMT_OFF  16777217
#define IDX_OFF  16777218
#define PERP_OFF 16842754

typedef _Float16 half8 __attribute__((ext_vector_type(8)));
typedef float f32x4 __attribute__((ext_vector_type(4)));

// LDS row stride for x tiles: 256 k + 8 pad halves = 264 (528B, 16B-aligned)
#define XROW_ 264
#define XLO_OFF_ (64 * XROW_)      // xs_lo starts here (halfs)

// ---------------- Kernel P: split embed into frag-order hi/lo + f32 norms ---
// ehi/elo layout: frag-major. For code-group g (16 codes), k-chunk kc (32 k),
// lane l: element j holds e[g*16 + (l&15)][kc*32 + (l>>4)*8 + j].
// Stored at half-offset ((g*8 + kc)*64 + l)*8 + j -> wave loads 1KB contiguous
// AND matches global_load_lds's (uniform base + lane*16B) dest rule exactly.
__global__ void prep_embed(const float* __restrict__ embed,
                           _Float16* __restrict__ ehi,
                           _Float16* __restrict__ elo,
                           float* __restrict__ normf) {
  int g = blockIdx.x;              // 64 blocks
  int tid = threadIdx.x;           // 256
  int w = tid >> 6, l = tid & 63;

#pragma unroll
  for (int ii = 0; ii < 2; ++ii) {
    int kc = w * 2 + ii;
    int code = g * 16 + (l & 15);
    int k0 = kc * 32 + (l >> 4) * 8;
    const float* src = embed + (size_t)code * D_ + k0;
    half8 hh, ll;
#pragma unroll
    for (int j = 0; j < 8; ++j) {
      float v = src[j];
      _Float16 h = (_Float16)v;
      _Float16 lo = (_Float16)(v - (float)h);
      hh[j] = h;
      ll[j] = lo;
    }
    size_t off = ((size_t)(g * 8 + kc) * 64 + l) * 8;
    *(half8*)(ehi + off) = hh;
    *(half8*)(elo + off) = ll;
  }

  // f64-accumulated norms (stored f32): code = g*16 + tid>>4, seg (tid&15)*16
  int code = g * 16 + (tid >> 4);
  int ks = (tid & 15) * 16;
  const float* src = embed + (size_t)code * D_ + ks;
  double s = 0.0;
#pragma unroll
  for (int j = 0; j < 16; ++j) {
    double v = src[j];
    s += v * v;
  }
#pragma unroll
  for (int m = 1; m < 16; m <<= 1) s += __shfl_xor(s, m, 64);
  if ((tid & 15) == 0) normf[code] = (float)s;
}

// async global->LDS, 16B per lane, dest = uniform base + lane*16
__device__ __forceinline__ void gld_lds16(const _Float16* gsrc_lane,
                                          _Float16* lds_base) {
  __builtin_amdgcn_global_load_lds(
      (const __attribute__((address_space(1))) void*)gsrc_lane,
      (__attribute__((address_space(3))) void*)lds_base, 16, 0, 0);
}

// ---------------- Kernel B: MFMA distance GEMM + argmin ---------------------
// 1024 blocks x 512 threads (8 waves). Block owns 64 points (one b, 64 t).
// x tile staged once in LDS as f16 hi/lo. Each wave owns 1 code-frag (16
// codes) per ng, 8 ngs -> 128 codes/wave, 8 waves -> 1024 (block reads the
// codebook exactly once). B stream: DMA'd into WAVE-PRIVATE double-buffered
// LDS via global_load_lds one step ahead (zero VGPR cost, no barriers in the
// loop), consumed with counted s_waitcnt vmcnt(2). acc = 4 x f32x4 = 16 AGPR.
// Fold pure f32, xn2-free: key = nrm - 2*dot.
__global__ __launch_bounds__(512, 2) void argmin_kernel(
    const float* __restrict__ inputs, const _Float16* __restrict__ ehi,
    const _Float16* __restrict__ elo, const float* __restrict__ normf,
    float* __restrict__ idx_out, int* __restrict__ counts,
    double* __restrict__ mse_acc) {
  __shared__ _Float16 xs[2 * 64 * XROW_];  // hi then lo, 67584 B
  __shared__ _Float16 ldsB[8 * 2048];      // 8 waves x (2 buf x 1024) 32768 B
  __shared__ float normf_lds[1024];        // 4096 B
  __shared__ double part[512];             // 4096 B (cand aliases it at tail)
  __shared__ double xn2s[64];              // 512 B   -> total 109,056 B

  float* candv = (float*)part;             // [8][64] floats, tail only
  int* candi = (int*)(part + 256);         // [8][64] ints, tail only

  int tid = threadIdx.x;
  int blk = blockIdx.x;            // point block: 64 points
  int b = blk >> 4, t0 = (blk & 15) * 64;
  size_t base = (size_t)b * DT_ + t0;

  // ---- stage x tile: f32 -> (hi,lo) f16, transpose [d][t] -> [t][k=d] ----
  {
    int t = tid & 63, dgrp = tid >> 6;      // 8 dgroups x 32 d
    const float* src = inputs + base + t;
    double s = 0.0;
#pragma unroll 4
    for (int i = 0; i < 16; ++i) {
      int d = dgrp * 32 + i * 2;
      float v0 = src[(size_t)d * T_];
      float v1 = src[(size_t)(d + 1) * T_];
      s += (double)v0 * v0 + (double)v1 * v1;
      _Float16 h0 = (_Float16)v0, h1 = (_Float16)v1;
      _Float16 e0 = (_Float16)(v0 - (float)h0);
      _Float16 e1 = (_Float16)(v1 - (float)h1);
      union {
        _Float16 h[2];
        unsigned u;
      } ph, pl;
      ph.h[0] = h0; ph.h[1] = h1;
      pl.h[0] = e0; pl.h[1] = e1;
      *(unsigned*)&xs[t * XROW_ + d] = ph.u;
      *(unsigned*)&xs[XLO_OFF_ + t * XROW_ + d] = pl.u;
    }
    part[tid] = s;
    ((float2*)normf_lds)[tid] = ((const float2*)normf)[tid];
  }
  __syncthreads();
  if (tid < 64) {
    double s = 0.0;
#pragma unroll
    for (int g = 0; g < 8; ++g) s += part[g * 64 + tid];
    xn2s[tid] = s;
  }
  __syncthreads();   // drains vmcnt to 0 (compiler) -> counted waits valid

  int w = tid >> 6, l = tid & 63;          // w 0..7 = wave's code group
  int lrow = l & 15;
  int lk = (l >> 4) * 8;
  _Float16* wB = ldsB + w * 2048;          // wave-private 4KB (2 bufs)

  // per-lane point slots: p_local = m*16 + (l>>4)*4 + r
  float bestv[4][4];
  int besti[4][4];
#pragma unroll
  for (int m = 0; m < 4; ++m)
#pragma unroll
    for (int r = 0; r < 4; ++r) {
      bestv[m][r] = 1e30f;
      besti[m][r] = 0;
    }

  f32x4 acc[4];
#pragma unroll
  for (int m = 0; m < 4; ++m) acc[m] = (f32x4){0.f, 0.f, 0.f, 0.f};

  // prologue: DMA step s=0 (ng=0 -> g=w, kc=0) into buf0
  {
    size_t off0 = ((size_t)(w * 8 + 0) * 64 + l) * 8;
    gld_lds16(ehi + off0, wB + 0);
    gld_lds16(elo + off0, wB + 512);
  }

#pragma unroll 1
  for (int s = 0; s < 64; ++s) {
    int kc = s & 7, ng = s >> 3;
    int p = s & 1;
    // issue DMA for step s+1 into the other buffer (read last iteration,
    // fully consumed: its ds_reads completed before the previous MFMAs)
    {
      int sn = (s + 1) & 63;
      int gn = (sn >> 3) * 8 + w, kcn = sn & 7;
      size_t offn = ((size_t)(gn * 8 + kcn) * 64 + l) * 8;
      _Float16* dst = wB + ((s + 1) & 1) * 1024;
      gld_lds16(ehi + offn, dst);
      gld_lds16(elo + offn, dst + 512);
    }
    // wait for step s's 2 chunks (the 2 just issued stay in flight)
    asm volatile("s_waitcnt vmcnt(2)" ::: "memory");

    half8 bh = *(const half8*)(wB + p * 1024 + l * 8);
    half8 bl = *(const half8*)(wB + p * 1024 + 512 + l * 8);
    half8 ah[4], al[4];
#pragma unroll
    for (int m = 0; m < 4; ++m) {
      const _Float16* pp = &xs[(m * 16 + lrow) * XROW_ + kc * 32 + lk];
      ah[m] = *(const half8*)pp;
      al[m] = *(const half8*)(pp + XLO_OFF_);
    }
    __builtin_amdgcn_s_setprio(1);
#pragma unroll
    for (int m = 0; m < 4; ++m) {
      acc[m] = __builtin_amdgcn_mfma_f32_16x16x32_f16(ah[m], bh, acc[m], 0, 0, 0);
      acc[m] = __builtin_amdgcn_mfma_f32_16x16x32_f16(al[m], bh, acc[m], 0, 0, 0);
      acc[m] = __builtin_amdgcn_mfma_f32_16x16x32_f16(ah[m], bl, acc[m], 0, 0, 0);
    }
    __builtin_amdgcn_s_setprio(0);

    if (kc == 7) {
      // ---- f32 fold: key = nrm - 2*dot (xn2-free; strict < keeps lowest
      // index because code index increases per thread over ngs) ----
      int c = (ng * 8 + w) * 16 + lrow;
      float nf = normf_lds[c];
#pragma unroll
      for (int m = 0; m < 4; ++m)
#pragma unroll
        for (int r = 0; r < 4; ++r) {
          float df = fmaf(-2.0f, acc[m][r], nf);
          if (df < bestv[m][r]) {
            bestv[m][r] = df;
            besti[m][r] = c;
          }
          acc[m][r] = 0.f;
        }
    }
  }

  // reduce across the 16 code-lanes of each quarter
#pragma unroll
  for (int msk = 1; msk < 16; msk <<= 1) {
#pragma unroll
    for (int m = 0; m < 4; ++m)
#pragma unroll
      for (int r = 0; r < 4; ++r) {
        float ov = __shfl_xor(bestv[m][r], msk, 64);
        int oi = __shfl_xor(besti[m][r], msk, 64);
        if (ov < bestv[m][r] || (ov == bestv[m][r] && oi < besti[m][r])) {
          bestv[m][r] = ov;
          besti[m][r] = oi;
        }
      }
  }
  if (lrow == 0) {
    int q = l >> 4;
#pragma unroll
    for (int m = 0; m < 4; ++m)
#pragma unroll
      for (int r = 0; r < 4; ++r) {
        candv[w * 64 + m * 16 + q * 4 + r] = bestv[m][r];
        candi[w * 64 + m * 16 + q * 4 + r] = besti[m][r];
      }
  }
  __syncthreads();

  if (tid < 64) {
    float bv = candv[tid];
    int bi = candi[tid];
#pragma unroll
    for (int w2 = 1; w2 < 8; ++w2) {
      float ov = candv[w2 * 64 + tid];
      int oi = candi[w2 * 64 + tid];
      if (ov < bv || (ov == bv && oi < bi)) {
        bv = ov;
        bi = oi;
      }
    }
    int p = blk * 64 + tid;
    idx_out[p] = (float)bi;
    atomicAdd(&counts[bi], 1);
    // MSE: dist = ||x||^2 + (nrm - 2*dot) = xn2 + key
    double s = xn2s[tid] + (double)bv;
    for (int msk = 32; msk; msk >>= 1) s += __shfl_down(s, msk, 64);
    if (tid == 0) atomicAdd(mse_acc, s);
  }
}

// ---------------- Kernel C: gather quantized rows, coalesced write ----------
__global__ __launch_bounds__(256) void quantize_kernel(
    const float* __restrict__ embed, const float* __restrict__ idx_f,
    float* __restrict__ qout) {
  __shared__ float qs[64 * 257];
  __shared__ int lidx[64];

  int tid = threadIdx.x;
  int bx = blockIdx.x;
  int b = bx >> 4;
  int t0 = (bx & 15) * 64;

  if (tid < 64) lidx[tid] = (int)idx_f[b * T_ + t0 + tid];
  __syncthreads();

#pragma unroll 4
  for (int p = 0; p < 64; ++p) {
    qs[p * 257 + tid] = embed[(size_t)lidx[p] * D_ + tid];
  }
  __syncthreads();

  size_t base = (size_t)b * DT_ + t0;
#pragma unroll 4
  for (int i = 0; i < 64; ++i) {
    int d = i * 4 + (tid >> 6);
    int p = tid & 63;
    qout[base + (size_t)d * T_ + p] = qs[p * 257 + d];
  }
}

// ---------------- Kernel D: finalize scalars --------------------------------
__global__ void finalize_kernel(const int* __restrict__ counts,
                                const double* __restrict__ mse_acc,
                                float* __restrict__ out) {
  int tid = threadIdx.x;  // 1024
  double p = (double)counts[tid] / (double)NPTS_;
  double s = p * log(p + 1e-10);
  for (int m = 32; m; m >>= 1) s += __shfl_down(s, m, 64);
  __shared__ double red[16];
  if ((tid & 63) == 0) red[tid >> 6] = s;
  __syncthreads();
  if (tid == 0) {
    double tot = 0.0;
    for (int i = 0; i < 16; ++i) tot += red[i];
    double mse = *mse_acc / (double)QSZ_;
    out[LOSS_OFF] = (float)(mse * 1.2);
    out[CMT_OFF] = (float)mse;
    out[PERP_OFF] = (float)exp(-tot);
  }
}

// ---------------- launch ----------------------------------------------------
extern "C" void kernel_launch(void* const* d_in, const int* in_sizes, int n_in,
                              void* d_out, int out_size, void* d_ws,
                              size_t ws_size, hipStream_t stream) {
  const float* inputs = (const float*)d_in[0];
  const float* embed = (const float*)d_in[1];
  float* out = (float*)d_out;

  char* ws = (char*)d_ws;
  _Float16* ehi = (_Float16*)ws;                         // 512 KB
  _Float16* elo = (_Float16*)(ws + 524288);              // 512 KB
  float* normf = (float*)(ws + 1048576);                 // 4 KB
  int* counts = (int*)(ws + 1048576 + 4096);             // 4 KB
  double* mse = (double*)(ws + 1048576 + 8192);          // 8 B

  hipMemsetAsync(ws + 1048576 + 4096, 0, 4096 + 8, stream);

  prep_embed<<<64, 256, 0, stream>>>(embed, ehi, elo, normf);
  argmin_kernel<<<1024, 512, 0, stream>>>(inputs, ehi, elo, normf,
                                          out + IDX_OFF, counts, mse);
  quantize_kernel<<<1024, 256, 0, stream>>>(embed, out + IDX_OFF, out);
  finalize_kernel<<<1, 1024, 0, stream>>>(counts, mse, out);
}

// Round 11
// 176.771 us; speedup vs baseline: 1.9198x; 1.1190x over previous
//
#include <hip/hip_runtime.h>

#define B_ 64
#define D_ 256
#define T_ 1024
#define NC_ 1024
#define DT_ (D_ * T_)              // 262144
#define NPTS_ (B_ * T_)            // 65536

#define QSZ_   16777216            // B*D*T
#define LOSS_OFF 16777216
#define CMT_OFF  16777217
#define IDX_OFF  16777218
#define PERP_OFF 16842754

typedef _Float16 half8 __attribute__((ext_vector_type(8)));
typedef float f32x4 __attribute__((ext_vector_type(4)));

// ---------------- Kernel P: split embed into frag-order hi/lo + f32 norms ---
// ehi/elo layout: frag-major. For code-group g (16 codes), k-chunk kc (32 k),
// lane l: element j holds e[g*16 + (l&15)][kc*32 + (l>>4)*8 + j].
// Stored at half-offset ((g*8 + kc)*64 + l)*8 + j -> 1KB contiguous per
// (g,kc) chunk AND matches global_load_lds (uniform base + lane*16B) exactly.
__global__ void prep_embed(const float* __restrict__ embed,
                           _Float16* __restrict__ ehi,
                           _Float16* __restrict__ elo,
                           float* __restrict__ normf) {
  int g = blockIdx.x;              // 64 blocks
  int tid = threadIdx.x;           // 256
  int w = tid >> 6, l = tid & 63;

#pragma unroll
  for (int ii = 0; ii < 2; ++ii) {
    int kc = w * 2 + ii;
    int code = g * 16 + (l & 15);
    int k0 = kc * 32 + (l >> 4) * 8;
    const float* src = embed + (size_t)code * D_ + k0;
    half8 hh, ll;
#pragma unroll
    for (int j = 0; j < 8; ++j) {
      float v = src[j];
      _Float16 h = (_Float16)v;
      _Float16 lo = (_Float16)(v - (float)h);
      hh[j] = h;
      ll[j] = lo;
    }
    size_t off = ((size_t)(g * 8 + kc) * 64 + l) * 8;
    *(half8*)(ehi + off) = hh;
    *(half8*)(elo + off) = ll;
  }

  // f64-accumulated norms (stored f32): code = g*16 + tid>>4, seg (tid&15)*16
  int code = g * 16 + (tid >> 4);
  int ks = (tid & 15) * 16;
  const float* src = embed + (size_t)code * D_ + ks;
  double s = 0.0;
#pragma unroll
  for (int j = 0; j < 16; ++j) {
    double v = src[j];
    s += v * v;
  }
#pragma unroll
  for (int m = 1; m < 16; m <<= 1) s += __shfl_xor(s, m, 64);
  if ((tid & 15) == 0) normf[code] = (float)s;
}

// async global->LDS, 16B per lane, dest = uniform base + lane*16
__device__ __forceinline__ void gld_lds16(const _Float16* gsrc_lane,
                                          _Float16* lds_base) {
  __builtin_amdgcn_global_load_lds(
      (const __attribute__((address_space(1))) void*)gsrc_lane,
      (__attribute__((address_space(3))) void*)lds_base, 16, 0, 0);
}

// ---------------- Kernel B: MFMA distance GEMM + argmin (m97 structure) -----
// 1024 blocks x 256 threads (4 waves). Block owns 64 points (one b, 64 t).
// INVERTED ROLES vs R5: A (x, hi/lo f16) lives in REGISTERS (each wave owns
// one 16-point M-frag = 16 half8 = 64 VGPR, loaded once in the prologue);
// B (codebook) streams through block-shared double-buffered LDS tiles of 16
// codes (16 KB/tile) via global_load_lds (zero VGPR), 64 tiles, one barrier
// per tile. All 4 waves consume the same B tile -> codebook read once per
// block; each wave folds its own 16 points (no cross-wave reduction).
// LDS ~37 KB -> 4 blocks/CU = 4 waves/SIMD; per SIMD per tile ~1860 cyc of
// MFMA covers the ~500 cyc DMA flight. Fold pure f32, xn2-free.
__global__ __launch_bounds__(256, 3) void argmin_kernel(
    const float* __restrict__ inputs, const _Float16* __restrict__ ehi,
    const _Float16* __restrict__ elo, const float* __restrict__ normf,
    float* __restrict__ idx_out, int* __restrict__ counts,
    double* __restrict__ mse_acc) {
  __shared__ _Float16 ldsB[2][8192];   // 2 buf x (hi 4096 | lo 4096) = 32 KB
  __shared__ float normf_lds[1024];    // 4 KB
  __shared__ double xn2w[64];          // 512 B -> total 37376 B

  int tid = threadIdx.x;
  int blk = blockIdx.x;            // point block: 64 points
  int b = blk >> 4, t0 = (blk & 15) * 64;
  int w = tid >> 6, l = tid & 63;

  // ---- prologue: load this wave's A m-frag (16 points x 256 k) to regs ----
  // lane l: point = w*16 + (l&15); k = kc*32 + (l>>4)*8 + j  (MFMA A layout)
  half8 ah[8], al[8];
  double xn2p = 0.0;
  {
    const float* xsrc = inputs + (size_t)b * DT_ + t0 + w * 16 + (l & 15);
    int kbase = (l >> 4) * 8;
#pragma unroll
    for (int kc = 0; kc < 8; ++kc) {
      half8 hh, ll;
#pragma unroll
      for (int j = 0; j < 8; ++j) {
        float v = xsrc[(size_t)(kc * 32 + kbase + j) * T_];
        xn2p += (double)v * v;
        _Float16 h = (_Float16)v;
        _Float16 lo = (_Float16)(v - (float)h);
        hh[j] = h;
        ll[j] = lo;
      }
      ah[kc] = hh;
      al[kc] = ll;
    }
  }
  // xn2 per point: reduce across the 4 k-quarters (lanes l, l^16, l^32, l^48)
  xn2p += __shfl_xor(xn2p, 16, 64);
  xn2p += __shfl_xor(xn2p, 32, 64);
  if (l < 16) xn2w[w * 16 + l] = xn2p;

  // stage f32 norms table (4 KB) + tile 0
  ((float4*)normf_lds)[tid] = ((const float4*)normf)[tid];
#pragma unroll
  for (int i = 0; i < 2; ++i) {
    int kc = w * 2 + i;
    size_t off = ((size_t)kc * 64 + l) * 8;   // tile 0
    gld_lds16(ehi + off, &ldsB[0][kc * 512]);
    gld_lds16(elo + off, &ldsB[0][4096 + kc * 512]);
  }
  __syncthreads();   // drains vmcnt -> tile 0 + normf + xn2w visible

  // per-lane state: acc row j -> point (l>>4)*4 + j; col -> code t*16+(l&15)
  float bestv[4];
  int besti[4];
#pragma unroll
  for (int j = 0; j < 4; ++j) {
    bestv[j] = 1e30f;
    besti[j] = 0;
  }

#pragma unroll 1
  for (int t = 0; t < 64; ++t) {
    int cur = t & 1, nxt = cur ^ 1;
    // issue next tile's DMA first (flies under this tile's MFMAs)
    if (t < 63) {
#pragma unroll
      for (int i = 0; i < 2; ++i) {
        int kc = w * 2 + i;
        size_t off = ((size_t)((t + 1) * 8 + kc) * 64 + l) * 8;
        gld_lds16(ehi + off, &ldsB[nxt][kc * 512]);
        gld_lds16(elo + off, &ldsB[nxt][4096 + kc * 512]);
      }
    }

    f32x4 acc = (f32x4){0.f, 0.f, 0.f, 0.f};
#pragma unroll
    for (int kc = 0; kc < 8; ++kc) {
      half8 bh = *(const half8*)&ldsB[cur][(kc * 64 + l) * 8];
      half8 bl = *(const half8*)&ldsB[cur][4096 + (kc * 64 + l) * 8];
      acc = __builtin_amdgcn_mfma_f32_16x16x32_f16(ah[kc], bh, acc, 0, 0, 0);
      acc = __builtin_amdgcn_mfma_f32_16x16x32_f16(al[kc], bh, acc, 0, 0, 0);
      acc = __builtin_amdgcn_mfma_f32_16x16x32_f16(ah[kc], bl, acc, 0, 0, 0);
    }

    // ---- f32 fold: key = nrm - 2*dot (xn2-free; strict < keeps low-index
    // ties because c strictly increases over t for each lane) ----
    {
      int c = t * 16 + (l & 15);
      float nf = normf_lds[c];
#pragma unroll
      for (int j = 0; j < 4; ++j) {
        float df = fmaf(-2.0f, acc[j], nf);
        if (df < bestv[j]) {
          bestv[j] = df;
          besti[j] = c;
        }
      }
    }
    __syncthreads();   // tile nxt DMA drained; buf cur free for overwrite
  }

  // reduce over the 16 code-lanes (codes c ≡ l&15 mod 16); butterfly leaves
  // every lane with the min for its 4 points
#pragma unroll
  for (int msk = 1; msk < 16; msk <<= 1) {
#pragma unroll
    for (int j = 0; j < 4; ++j) {
      float ov = __shfl_xor(bestv[j], msk, 64);
      int oi = __shfl_xor(besti[j], msk, 64);
      if (ov < bestv[j] || (ov == bestv[j] && oi < besti[j])) {
        bestv[j] = ov;
        besti[j] = oi;
      }
    }
  }

  if ((l & 15) == 0) {
    // this lane owns points p = w*16 + (l>>4)*4 + j, j=0..3 (consecutive)
    float4 iw;
    double s = 0.0;
#pragma unroll
    for (int j = 0; j < 4; ++j) {
      int p = (l >> 4) * 4 + j;
      iw[j == 0 ? 0 : (j == 1 ? 1 : (j == 2 ? 2 : 3))] = (float)besti[j];
      atomicAdd(&counts[besti[j]], 1);
      s += xn2w[w * 16 + p] + (double)bestv[j];   // dist = xn2 + key
    }
    *(float4*)&idx_out[blk * 64 + w * 16 + (l >> 4) * 4] = iw;
    // reduce s across lanes 0,16,32,48 (masks 16/32 stay within l&15==0)
    s += __shfl_xor(s, 16, 64);
    s += __shfl_xor(s, 32, 64);
    if (l == 0) atomicAdd(mse_acc, s);
  }
}

// ---------------- Kernel C: gather quantized rows, coalesced write ----------
__global__ __launch_bounds__(256) void quantize_kernel(
    const float* __restrict__ embed, const float* __restrict__ idx_f,
    float* __restrict__ qout) {
  __shared__ float qs[64 * 257];
  __shared__ int lidx[64];

  int tid = threadIdx.x;
  int bx = blockIdx.x;
  int b = bx >> 4;
  int t0 = (bx & 15) * 64;

  if (tid < 64) lidx[tid] = (int)idx_f[b * T_ + t0 + tid];
  __syncthreads();

#pragma unroll 4
  for (int p = 0; p < 64; ++p) {
    qs[p * 257 + tid] = embed[(size_t)lidx[p] * D_ + tid];
  }
  __syncthreads();

  size_t base = (size_t)b * DT_ + t0;
#pragma unroll 4
  for (int i = 0; i < 64; ++i) {
    int d = i * 4 + (tid >> 6);
    int p = tid & 63;
    qout[base + (size_t)d * T_ + p] = qs[p * 257 + d];
  }
}

// ---------------- Kernel D: finalize scalars --------------------------------
__global__ void finalize_kernel(const int* __restrict__ counts,
                                const double* __restrict__ mse_acc,
                                float* __restrict__ out) {
  int tid = threadIdx.x;  // 1024
  double p = (double)counts[tid] / (double)NPTS_;
  double s = p * log(p + 1e-10);
  for (int m = 32; m; m >>= 1) s += __shfl_down(s, m, 64);
  __shared__ double red[16];
  if ((tid & 63) == 0) red[tid >> 6] = s;
  __syncthreads();
  if (tid == 0) {
    double tot = 0.0;
    for (int i = 0; i < 16; ++i) tot += red[i];
    double mse = *mse_acc / (double)QSZ_;
    out[LOSS_OFF] = (float)(mse * 1.2);
    out[CMT_OFF] = (float)mse;
    out[PERP_OFF] = (float)exp(-tot);
  }
}

// ---------------- launch ----------------------------------------------------
extern "C" void kernel_launch(void* const* d_in, const int* in_sizes, int n_in,
                              void* d_out, int out_size, void* d_ws,
                              size_t ws_size, hipStream_t stream) {
  const float* inputs = (const float*)d_in[0];
  const float* embed = (const float*)d_in[1];
  float* out = (float*)d_out;

  char* ws = (char*)d_ws;
  _Float16* ehi = (_Float16*)ws;                         // 512 KB
  _Float16* elo = (_Float16*)(ws + 524288);              // 512 KB
  float* normf = (float*)(ws + 1048576);                 // 4 KB
  int* counts = (int*)(ws + 1048576 + 4096);             // 4 KB
  double* mse = (double*)(ws + 1048576 + 8192);          // 8 B

  hipMemsetAsync(ws + 1048576 + 4096, 0, 4096 + 8, stream);

  prep_embed<<<64, 256, 0, stream>>>(embed, ehi, elo, normf);
  argmin_kernel<<<1024, 256, 0, stream>>>(inputs, ehi, elo, normf,
                                          out + IDX_OFF, counts, mse);
  quantize_kernel<<<1024, 256, 0, stream>>>(embed, out + IDX_OFF, out);
  finalize_kernel<<<1, 1024, 0, stream>>>(counts, mse, out);
}

// Round 12
// 167.539 us; speedup vs baseline: 2.0256x; 1.0551x over previous
//
#include <hip/hip_runtime.h>

#define B_ 64
#define D_ 256
#define T_ 1024
#define NC_ 1024
#define DT_ (D_ * T_)              // 262144
#define NPTS_ (B_ * T_)            // 65536

#define QSZ_   16777216            // B*D*T
#define LOSS_OFF 16777216
#define CMT_OFF  16777217
#define IDX_OFF  16777218
#define PERP_OFF 16842754

typedef _Float16 half8 __attribute__((ext_vector_type(8)));
typedef float f32x4 __attribute__((ext_vector_type(4)));

// ---------------- Kernel P: split embed into frag-order hi/lo + f32 norms ---
// ehi/elo layout: frag-major. For code-group g (16 codes), k-chunk kc (32 k),
// lane l: element j holds e[g*16 + (l&15)][kc*32 + (l>>4)*8 + j].
// Stored at half-offset ((g*8 + kc)*64 + l)*8 + j -> 1KB contiguous per
// (g,kc) chunk AND matches global_load_lds (uniform base + lane*16B) exactly.
__global__ void prep_embed(const float* __restrict__ embed,
                           _Float16* __restrict__ ehi,
                           _Float16* __restrict__ elo,
                           float* __restrict__ normf) {
  int g = blockIdx.x;              // 64 blocks
  int tid = threadIdx.x;           // 256
  int w = tid >> 6, l = tid & 63;

#pragma unroll
  for (int ii = 0; ii < 2; ++ii) {
    int kc = w * 2 + ii;
    int code = g * 16 + (l & 15);
    int k0 = kc * 32 + (l >> 4) * 8;
    const float* src = embed + (size_t)code * D_ + k0;
    half8 hh, ll;
#pragma unroll
    for (int j = 0; j < 8; ++j) {
      float v = src[j];
      _Float16 h = (_Float16)v;
      _Float16 lo = (_Float16)(v - (float)h);
      hh[j] = h;
      ll[j] = lo;
    }
    size_t off = ((size_t)(g * 8 + kc) * 64 + l) * 8;
    *(half8*)(ehi + off) = hh;
    *(half8*)(elo + off) = ll;
  }

  // f64-accumulated norms (stored f32): code = g*16 + tid>>4, seg (tid&15)*16
  int code = g * 16 + (tid >> 4);
  int ks = (tid & 15) * 16;
  const float* src = embed + (size_t)code * D_ + ks;
  double s = 0.0;
#pragma unroll
  for (int j = 0; j < 16; ++j) {
    double v = src[j];
    s += v * v;
  }
#pragma unroll
  for (int m = 1; m < 16; m <<= 1) s += __shfl_xor(s, m, 64);
  if ((tid & 15) == 0) normf[code] = (float)s;
}

// async global->LDS, 16B per lane, dest = uniform base + lane*16
__device__ __forceinline__ void gld_lds16(const _Float16* gsrc_lane,
                                          _Float16* lds_base) {
  __builtin_amdgcn_global_load_lds(
      (const __attribute__((address_space(1))) void*)gsrc_lane,
      (__attribute__((address_space(3))) void*)lds_base, 16, 0, 0);
}

// ---------------- Kernel B: MFMA distance GEMM + argmin ---------------------
// 512 blocks x 256 threads (4 waves). Block owns 128 points (one b, 128 t);
// each wave owns 32 points = 2 M-frags, held ENTIRELY IN REGISTERS as hi/lo
// f16 (ah/al[2][8] = 128 VGPR, statically indexed, loaded once in prologue).
// B (codebook) streams through block-shared double-buffered LDS tiles of 16
// codes via global_load_lds (zero VGPR, R11-proven 0-conflict layout), 64
// tiles, one barrier per tile. 16 ds_read_b128 feed 48 MFMAs per wave-tile
// (1:3) -> LDS port ~41 us < MFMA floor ~50 us: MFMA-bound at last.
// Fold pure f32, xn2-free: key = nrm - 2*dot.
__global__ __launch_bounds__(256, 2) void argmin_kernel(
    const float* __restrict__ inputs, const _Float16* __restrict__ ehi,
    const _Float16* __restrict__ elo, const float* __restrict__ normf,
    float* __restrict__ idx_out, int* __restrict__ counts,
    double* __restrict__ mse_acc) {
  __shared__ _Float16 ldsB[2][8192];   // 2 buf x (hi 4096 | lo 4096) = 32 KB
  __shared__ float normf_lds[1024];    // 4 KB
  __shared__ double xn2w[128];         // 1 KB -> total 37888 B

  int tid = threadIdx.x;
  int blk = blockIdx.x;            // point block: 128 points
  int b = blk >> 3, t0 = (blk & 7) * 128;
  int w = tid >> 6, l = tid & 63;

  // ---- prologue: load this wave's 2 A m-frags (32 points x 256 k) to regs
  // lane l, frag m: point = w*32 + m*16 + (l&15); k = kc*32 + (l>>4)*8 + j
  half8 ah[2][8], al[2][8];
  double xn2p0 = 0.0, xn2p1 = 0.0;
  {
    int kq = (l >> 4) * 8;
    const float* xcol = inputs + (size_t)b * DT_ + t0 + w * 32 + (l & 15);
#pragma unroll
    for (int m = 0; m < 2; ++m) {
      const float* src = xcol + m * 16;
#pragma unroll
      for (int kc = 0; kc < 8; ++kc) {
        half8 hh, ll;
#pragma unroll
        for (int j = 0; j < 8; ++j) {
          float v = src[(size_t)(kc * 32 + kq + j) * T_];
          if (m == 0) xn2p0 += (double)v * v; else xn2p1 += (double)v * v;
          _Float16 h = (_Float16)v;
          hh[j] = h;
          ll[j] = (_Float16)(v - (float)h);
        }
        ah[m][kc] = hh;
        al[m][kc] = ll;
      }
    }
  }
  // full xn2 per point: combine the 4 k-quarters (lanes l, l^16, l^32, l^48)
  xn2p0 += __shfl_xor(xn2p0, 16, 64);
  xn2p0 += __shfl_xor(xn2p0, 32, 64);
  xn2p1 += __shfl_xor(xn2p1, 16, 64);
  xn2p1 += __shfl_xor(xn2p1, 32, 64);
  if (l < 16) {
    xn2w[w * 32 + l] = xn2p0;
    xn2w[w * 32 + 16 + l] = xn2p1;
  }

  // stage f32 norms table (4 KB) + B tile 0
  ((float4*)normf_lds)[tid] = ((const float4*)normf)[tid];
#pragma unroll
  for (int i = 0; i < 2; ++i) {
    int kc = w * 2 + i;
    size_t off = ((size_t)kc * 64 + l) * 8;   // tile 0 = code-group 0
    gld_lds16(ehi + off, &ldsB[0][kc * 512]);
    gld_lds16(elo + off, &ldsB[0][4096 + kc * 512]);
  }
  __syncthreads();   // drains vmcnt -> tile 0 + normf + xn2w visible

  // per-lane slots: frag m, row j -> point w*32 + m*16 + (l>>4)*4 + j
  float bestv[2][4];
  int besti[2][4];
#pragma unroll
  for (int m = 0; m < 2; ++m)
#pragma unroll
    for (int j = 0; j < 4; ++j) {
      bestv[m][j] = 1e30f;
      besti[m][j] = 0;
    }

#pragma unroll 1
  for (int t = 0; t < 64; ++t) {
    int cur = t & 1, nxt = cur ^ 1;
    // issue next tile's DMA first (flies under this tile's 48 MFMAs)
    if (t < 63) {
#pragma unroll
      for (int i = 0; i < 2; ++i) {
        int kc = w * 2 + i;
        size_t off = ((size_t)((t + 1) * 8 + kc) * 64 + l) * 8;
        gld_lds16(ehi + off, &ldsB[nxt][kc * 512]);
        gld_lds16(elo + off, &ldsB[nxt][4096 + kc * 512]);
      }
    }

    f32x4 acc0 = (f32x4){0.f, 0.f, 0.f, 0.f};
    f32x4 acc1 = (f32x4){0.f, 0.f, 0.f, 0.f};
#pragma unroll
    for (int kc = 0; kc < 8; ++kc) {
      half8 bh = *(const half8*)&ldsB[cur][(kc * 64 + l) * 8];
      half8 bl = *(const half8*)&ldsB[cur][4096 + (kc * 64 + l) * 8];
      acc0 = __builtin_amdgcn_mfma_f32_16x16x32_f16(ah[0][kc], bh, acc0, 0, 0, 0);
      acc1 = __builtin_amdgcn_mfma_f32_16x16x32_f16(ah[1][kc], bh, acc1, 0, 0, 0);
      acc0 = __builtin_amdgcn_mfma_f32_16x16x32_f16(al[0][kc], bh, acc0, 0, 0, 0);
      acc1 = __builtin_amdgcn_mfma_f32_16x16x32_f16(al[1][kc], bh, acc1, 0, 0, 0);
      acc0 = __builtin_amdgcn_mfma_f32_16x16x32_f16(ah[0][kc], bl, acc0, 0, 0, 0);
      acc1 = __builtin_amdgcn_mfma_f32_16x16x32_f16(ah[1][kc], bl, acc1, 0, 0, 0);
    }

    // ---- f32 fold: key = nrm - 2*dot (xn2-free; strict < keeps low-index
    // ties because c strictly increases over t for each lane) ----
    {
      int c = t * 16 + (l & 15);
      float nf = normf_lds[c];
#pragma unroll
      for (int j = 0; j < 4; ++j) {
        float df0 = fmaf(-2.0f, acc0[j], nf);
        if (df0 < bestv[0][j]) {
          bestv[0][j] = df0;
          besti[0][j] = c;
        }
        float df1 = fmaf(-2.0f, acc1[j], nf);
        if (df1 < bestv[1][j]) {
          bestv[1][j] = df1;
          besti[1][j] = c;
        }
      }
    }
    __syncthreads();   // tile nxt DMA drained; buf cur free for overwrite
  }

  // reduce over the 16 code-lanes; butterfly leaves every lane with the min
#pragma unroll
  for (int msk = 1; msk < 16; msk <<= 1) {
#pragma unroll
    for (int m = 0; m < 2; ++m)
#pragma unroll
      for (int j = 0; j < 4; ++j) {
        float ov = __shfl_xor(bestv[m][j], msk, 64);
        int oi = __shfl_xor(besti[m][j], msk, 64);
        if (ov < bestv[m][j] || (ov == bestv[m][j] && oi < besti[m][j])) {
          bestv[m][j] = ov;
          besti[m][j] = oi;
        }
      }
  }

  if ((l & 15) == 0) {
    int q = l >> 4;
    double s = 0.0;
#pragma unroll
    for (int m = 0; m < 2; ++m) {
      float4 iw;
#pragma unroll
      for (int j = 0; j < 4; ++j) {
        int bi = besti[m][j];
        iw[j] = (float)bi;
        atomicAdd(&counts[bi], 1);
        s += xn2w[w * 32 + m * 16 + q * 4 + j] + (double)bestv[m][j];
      }
      *(float4*)&idx_out[blk * 128 + w * 32 + m * 16 + q * 4] = iw;
    }
    // reduce s across lanes 0,16,32,48 (xor 16/32 stays in l&15==0 set)
    s += __shfl_xor(s, 16, 64);
    s += __shfl_xor(s, 32, 64);
    if (l == 0) atomicAdd(mse_acc, s);
  }
}

// ---------------- Kernel C: gather quantized rows, coalesced write ----------
__global__ __launch_bounds__(256) void quantize_kernel(
    const float* __restrict__ embed, const float* __restrict__ idx_f,
    float* __restrict__ qout) {
  __shared__ float qs[64 * 257];
  __shared__ int lidx[64];

  int tid = threadIdx.x;
  int bx = blockIdx.x;
  int b = bx >> 4;
  int t0 = (bx & 15) * 64;

  if (tid < 64) lidx[tid] = (int)idx_f[b * T_ + t0 + tid];
  __syncthreads();

#pragma unroll 4
  for (int p = 0; p < 64; ++p) {
    qs[p * 257 + tid] = embed[(size_t)lidx[p] * D_ + tid];
  }
  __syncthreads();

  size_t base = (size_t)b * DT_ + t0;
#pragma unroll 4
  for (int i = 0; i < 64; ++i) {
    int d = i * 4 + (tid >> 6);
    int p = tid & 63;
    qout[base + (size_t)d * T_ + p] = qs[p * 257 + d];
  }
}

// ---------------- Kernel D: finalize scalars --------------------------------
__global__ void finalize_kernel(const int* __restrict__ counts,
                                const double* __restrict__ mse_acc,
                                float* __restrict__ out) {
  int tid = threadIdx.x;  // 1024
  double p = (double)counts[tid] / (double)NPTS_;
  double s = p * log(p + 1e-10);
  for (int m = 32; m; m >>= 1) s += __shfl_down(s, m, 64);
  __shared__ double red[16];
  if ((tid & 63) == 0) red[tid >> 6] = s;
  __syncthreads();
  if (tid == 0) {
    double tot = 0.0;
    for (int i = 0; i < 16; ++i) tot += red[i];
    double mse = *mse_acc / (double)QSZ_;
    out[LOSS_OFF] = (float)(mse * 1.2);
    out[CMT_OFF] = (float)mse;
    out[PERP_OFF] = (float)exp(-tot);
  }
}

// ---------------- launch ----------------------------------------------------
extern "C" void kernel_launch(void* const* d_in, const int* in_sizes, int n_in,
                              void* d_out, int out_size, void* d_ws,
                              size_t ws_size, hipStream_t stream) {
  const float* inputs = (const float*)d_in[0];
  const float* embed = (const float*)d_in[1];
  float* out = (float*)d_out;

  char* ws = (char*)d_ws;
  _Float16* ehi = (_Float16*)ws;                         // 512 KB
  _Float16* elo = (_Float16*)(ws + 524288);              // 512 KB
  float* normf = (float*)(ws + 1048576);                 // 4 KB
  int* counts = (int*)(ws + 1048576 + 4096);             // 4 KB
  double* mse = (double*)(ws + 1048576 + 8192);          // 8 B

  hipMemsetAsync(ws + 1048576 + 4096, 0, 4096 + 8, stream);

  prep_embed<<<64, 256, 0, stream>>>(embed, ehi, elo, normf);
  argmin_kernel<<<512, 256, 0, stream>>>(inputs, ehi, elo, normf,
                                         out + IDX_OFF, counts, mse);
  quantize_kernel<<<1024, 256, 0, stream>>>(embed, out + IDX_OFF, out);
  finalize_kernel<<<1, 1024, 0, stream>>>(counts, mse, out);
}

// Round 13
// 163.336 us; speedup vs baseline: 2.0777x; 1.0257x over previous
//
#include <hip/hip_runtime.h>

#define B_ 64
#define D_ 256
#define T_ 1024
#define NC_ 1024
#define DT_ (D_ * T_)              // 262144
#define NPTS_ (B_ * T_)            // 65536

#define QSZ_   16777216            // B*D*T
#define LOSS_OFF 16777216
#define CMT_OFF  16777217
#define IDX_OFF  16777218
#define PERP_OFF 16842754

typedef _Float16 half8 __attribute__((ext_vector_type(8)));
typedef float f32x4 __attribute__((ext_vector_type(4)));

// ---------------- Kernel P: split embed into frag-order hi/lo + f32 norms ---
__global__ void prep_embed(const float* __restrict__ embed,
                           _Float16* __restrict__ ehi,
                           _Float16* __restrict__ elo,
                           float* __restrict__ normf) {
  int g = blockIdx.x;              // 64 blocks
  int tid = threadIdx.x;           // 256
  int w = tid >> 6, l = tid & 63;

#pragma unroll
  for (int ii = 0; ii < 2; ++ii) {
    int kc = w * 2 + ii;
    int code = g * 16 + (l & 15);
    int k0 = kc * 32 + (l >> 4) * 8;
    const float* src = embed + (size_t)code * D_ + k0;
    half8 hh, ll;
#pragma unroll
    for (int j = 0; j < 8; ++j) {
      float v = src[j];
      _Float16 h = (_Float16)v;
      _Float16 lo = (_Float16)(v - (float)h);
      hh[j] = h;
      ll[j] = lo;
    }
    size_t off = ((size_t)(g * 8 + kc) * 64 + l) * 8;
    *(half8*)(ehi + off) = hh;
    *(half8*)(elo + off) = ll;
  }

  int code = g * 16 + (tid >> 4);
  int ks = (tid & 15) * 16;
  const float* src = embed + (size_t)code * D_ + ks;
  double s = 0.0;
#pragma unroll
  for (int j = 0; j < 16; ++j) {
    double v = src[j];
    s += v * v;
  }
#pragma unroll
  for (int m = 1; m < 16; m <<= 1) s += __shfl_xor(s, m, 64);
  if ((tid & 15) == 0) normf[code] = (float)s;
}

// async global->LDS, 16B per lane, dest = uniform base + lane*16
__device__ __forceinline__ void gld_lds16(const _Float16* gsrc_lane,
                                          _Float16* lds_base) {
  __builtin_amdgcn_global_load_lds(
      (const __attribute__((address_space(1))) void*)gsrc_lane,
      (__attribute__((address_space(3))) void*)lds_base, 16, 0, 0);
}

// ---------------- Kernel B: MFMA distance GEMM + argmin ---------------------
// 512 blocks x 256 threads (4 waves). A (32 pts/wave) in registers; B streams
// through a ring of 3 block-shared LDS tile buffers via global_load_lds with
// T3/T4-minimal schedule: counted vmcnt(4) + raw s_barrier (no drain) so the
// next tile's DMA stays in flight across the barrier; lgkmcnt(0) at iter end
// guarantees NBUF=3 buffer-reuse safety. setprio(1) around the MFMA cluster.
__global__ __launch_bounds__(256, 2) void argmin_kernel(
    const float* __restrict__ inputs, const _Float16* __restrict__ ehi,
    const _Float16* __restrict__ elo, const float* __restrict__ normf,
    float* __restrict__ idx_out, int* __restrict__ counts,
    double* __restrict__ mse_acc) {
  __shared__ _Float16 ldsB[3][8192];   // 3 bufs x (hi 4096 | lo 4096) = 48 KB
  __shared__ float normf_lds[1024];    // 4 KB
  __shared__ double xn2w[128];         // 1 KB -> total 54272 B

  int tid = threadIdx.x;
  int blk = blockIdx.x;            // point block: 128 points
  int b = blk >> 3, t0 = (blk & 7) * 128;
  int w = tid >> 6, l = tid & 63;

  // ---- issue tile-0 DMA first: flies under the whole A-prologue ----
#pragma unroll
  for (int i = 0; i < 2; ++i) {
    int kc = w * 2 + i;
    size_t off = ((size_t)kc * 64 + l) * 8;   // tile 0 = code-group 0
    gld_lds16(ehi + off, &ldsB[0][kc * 512]);
    gld_lds16(elo + off, &ldsB[0][4096 + kc * 512]);
  }

  // ---- prologue: this wave's 2 A m-frags (32 points x 256 k) to registers
  half8 ah[2][8], al[2][8];
  double xn2p0 = 0.0, xn2p1 = 0.0;
  {
    int kq = (l >> 4) * 8;
    const float* xcol = inputs + (size_t)b * DT_ + t0 + w * 32 + (l & 15);
#pragma unroll
    for (int m = 0; m < 2; ++m) {
      const float* src = xcol + m * 16;
#pragma unroll
      for (int kc = 0; kc < 8; ++kc) {
        half8 hh, ll;
#pragma unroll
        for (int j = 0; j < 8; ++j) {
          float v = src[(size_t)(kc * 32 + kq + j) * T_];
          if (m == 0) xn2p0 += (double)v * v; else xn2p1 += (double)v * v;
          _Float16 h = (_Float16)v;
          hh[j] = h;
          ll[j] = (_Float16)(v - (float)h);
        }
        ah[m][kc] = hh;
        al[m][kc] = ll;
      }
    }
  }
  xn2p0 += __shfl_xor(xn2p0, 16, 64);
  xn2p0 += __shfl_xor(xn2p0, 32, 64);
  xn2p1 += __shfl_xor(xn2p1, 16, 64);
  xn2p1 += __shfl_xor(xn2p1, 32, 64);
  if (l < 16) {
    xn2w[w * 32 + l] = xn2p0;
    xn2w[w * 32 + 16 + l] = xn2p1;
  }
  ((float4*)normf_lds)[tid] = ((const float4*)normf)[tid];
  __syncthreads();   // full drain: vmcnt=0 at loop entry; tile 0 ready

  float bestv[2][4];
  int besti[2][4];
#pragma unroll
  for (int m = 0; m < 2; ++m)
#pragma unroll
    for (int j = 0; j < 4; ++j) {
      bestv[m][j] = 1e30f;
      besti[m][j] = 0;
    }

  _Float16* rd = &ldsB[0][0];
  _Float16* wr = &ldsB[1][0];
  _Float16* sp = &ldsB[2][0];

#pragma unroll 1
  for (int t = 0; t < 64; ++t) {
    // 1) issue next tile's DMA into wr (stays in flight across the barrier)
    {
      int tn = (t + 1) & 63;       // t=63 wraps: harmless refetch of tile 0
#pragma unroll
      for (int i = 0; i < 2; ++i) {
        int kc = w * 2 + i;
        size_t off = ((size_t)(tn * 8 + kc) * 64 + l) * 8;
        gld_lds16(ehi + off, wr + kc * 512);
        gld_lds16(elo + off, wr + 4096 + kc * 512);
      }
    }
    // 2) counted wait: own tile-t writes done; 4 just-issued stay in flight
    asm volatile("s_waitcnt vmcnt(4)" ::: "memory");
    // 3) raw barrier (no drain): all waves' tile-t writes now visible
    __builtin_amdgcn_s_barrier();
    __builtin_amdgcn_sched_barrier(0);

    // 4) consume tile t
    f32x4 acc0 = (f32x4){0.f, 0.f, 0.f, 0.f};
    f32x4 acc1 = (f32x4){0.f, 0.f, 0.f, 0.f};
    __builtin_amdgcn_s_setprio(1);
#pragma unroll
    for (int kc = 0; kc < 8; ++kc) {
      half8 bh = *(const half8*)(rd + (kc * 64 + l) * 8);
      half8 bl = *(const half8*)(rd + 4096 + (kc * 64 + l) * 8);
      acc0 = __builtin_amdgcn_mfma_f32_16x16x32_f16(ah[0][kc], bh, acc0, 0, 0, 0);
      acc1 = __builtin_amdgcn_mfma_f32_16x16x32_f16(ah[1][kc], bh, acc1, 0, 0, 0);
      acc0 = __builtin_amdgcn_mfma_f32_16x16x32_f16(al[0][kc], bh, acc0, 0, 0, 0);
      acc1 = __builtin_amdgcn_mfma_f32_16x16x32_f16(al[1][kc], bh, acc1, 0, 0, 0);
      acc0 = __builtin_amdgcn_mfma_f32_16x16x32_f16(ah[0][kc], bl, acc0, 0, 0, 0);
      acc1 = __builtin_amdgcn_mfma_f32_16x16x32_f16(ah[1][kc], bl, acc1, 0, 0, 0);
    }
    __builtin_amdgcn_s_setprio(0);

    // f32 fold: key = nrm - 2*dot (xn2-free; strict < keeps low-index ties)
    {
      int c = t * 16 + (l & 15);
      float nf = normf_lds[c];
#pragma unroll
      for (int j = 0; j < 4; ++j) {
        float df0 = fmaf(-2.0f, acc0[j], nf);
        if (df0 < bestv[0][j]) {
          bestv[0][j] = df0;
          besti[0][j] = c;
        }
        float df1 = fmaf(-2.0f, acc1[j], nf);
        if (df1 < bestv[1][j]) {
          bestv[1][j] = df1;
          besti[1][j] = c;
        }
      }
    }
    // 5) drain our ds_reads (buffer-reuse safety, NBUF=3 proof)
    asm volatile("s_waitcnt lgkmcnt(0)" ::: "memory");

    _Float16* old_rd = rd;
    rd = wr;
    wr = sp;
    sp = old_rd;
  }
  asm volatile("s_waitcnt vmcnt(0)" ::: "memory");   // drain wrap DMA

  // butterfly min over the 16 code-lanes
#pragma unroll
  for (int msk = 1; msk < 16; msk <<= 1) {
#pragma unroll
    for (int m = 0; m < 2; ++m)
#pragma unroll
      for (int j = 0; j < 4; ++j) {
        float ov = __shfl_xor(bestv[m][j], msk, 64);
        int oi = __shfl_xor(besti[m][j], msk, 64);
        if (ov < bestv[m][j] || (ov == bestv[m][j] && oi < besti[m][j])) {
          bestv[m][j] = ov;
          besti[m][j] = oi;
        }
      }
  }

  if ((l & 15) == 0) {
    int q = l >> 4;
    double s = 0.0;
#pragma unroll
    for (int m = 0; m < 2; ++m) {
      float4 iw;
#pragma unroll
      for (int j = 0; j < 4; ++j) {
        int bi = besti[m][j];
        iw[j] = (float)bi;
        atomicAdd(&counts[bi], 1);
        s += xn2w[w * 32 + m * 16 + q * 4 + j] + (double)bestv[m][j];
      }
      *(float4*)&idx_out[blk * 128 + w * 32 + m * 16 + q * 4] = iw;
    }
    s += __shfl_xor(s, 16, 64);
    s += __shfl_xor(s, 32, 64);
    if (l == 0) atomicAdd(mse_acc, s);
  }
}

// ---------------- Kernel C: gather quantized rows, coalesced write ----------
__global__ __launch_bounds__(256) void quantize_kernel(
    const float* __restrict__ embed, const float* __restrict__ idx_f,
    float* __restrict__ qout) {
  __shared__ float qs[64 * 257];
  __shared__ int lidx[64];

  int tid = threadIdx.x;
  int bx = blockIdx.x;
  int b = bx >> 4;
  int t0 = (bx & 15) * 64;

  if (tid < 64) lidx[tid] = (int)idx_f[b * T_ + t0 + tid];
  __syncthreads();

#pragma unroll 4
  for (int p = 0; p < 64; ++p) {
    qs[p * 257 + tid] = embed[(size_t)lidx[p] * D_ + tid];
  }
  __syncthreads();

  size_t base = (size_t)b * DT_ + t0;
#pragma unroll 4
  for (int i = 0; i < 64; ++i) {
    int d = i * 4 + (tid >> 6);
    int p = tid & 63;
    qout[base + (size_t)d * T_ + p] = qs[p * 257 + d];
  }
}

// ---------------- Kernel D: finalize scalars --------------------------------
__global__ void finalize_kernel(const int* __restrict__ counts,
                                const double* __restrict__ mse_acc,
                                float* __restrict__ out) {
  int tid = threadIdx.x;  // 1024
  double p = (double)counts[tid] / (double)NPTS_;
  double s = p * log(p + 1e-10);
  for (int m = 32; m; m >>= 1) s += __shfl_down(s, m, 64);
  __shared__ double red[16];
  if ((tid & 63) == 0) red[tid >> 6] = s;
  __syncthreads();
  if (tid == 0) {
    double tot = 0.0;
    for (int i = 0; i < 16; ++i) tot += red[i];
    double mse = *mse_acc / (double)QSZ_;
    out[LOSS_OFF] = (float)(mse * 1.2);
    out[CMT_OFF] = (float)mse;
    out[PERP_OFF] = (float)exp(-tot);
  }
}

// ---------------- launch ----------------------------------------------------
extern "C" void kernel_launch(void* const* d_in, const int* in_sizes, int n_in,
                              void* d_out, int out_size, void* d_ws,
                              size_t ws_size, hipStream_t stream) {
  const float* inputs = (const float*)d_in[0];
  const float* embed = (const float*)d_in[1];
  float* out = (float*)d_out;

  char* ws = (char*)d_ws;
  _Float16* ehi = (_Float16*)ws;                         // 512 KB
  _Float16* elo = (_Float16*)(ws + 524288);              // 512 KB
  float* normf = (float*)(ws + 1048576);                 // 4 KB
  int* counts = (int*)(ws + 1048576 + 4096);             // 4 KB
  double* mse = (double*)(ws + 1048576 + 8192);          // 8 B

  hipMemsetAsync(ws + 1048576 + 4096, 0, 4096 + 8, stream);

  prep_embed<<<64, 256, 0, stream>>>(embed, ehi, elo, normf);
  argmin_kernel<<<512, 256, 0, stream>>>(inputs, ehi, elo, normf,
                                         out + IDX_OFF, counts, mse);
  quantize_kernel<<<1024, 256, 0, stream>>>(embed, out + IDX_OFF, out);
  finalize_kernel<<<1, 1024, 0, stream>>>(counts, mse, out);
}